// Round 1
// baseline (2335.408 us; speedup 1.0000x reference)
//
#include <hip/hip_runtime.h>

constexpr int B   = 2;
constexpr int T   = 2048;
constexpr int C   = 2048;
constexpr int H   = 32;
constexpr int HKV = 8;
constexpr int D   = 64;
constexpr float SCALE = 0.125f; // 1/sqrt(64)

// ---------------------------------------------------------------------------
// Generic NT SGEMM body: Y[m][n] = sum_k X[m][k] * W[n][k]
// 128x128 tile, BK=16, 256 threads, 8x8 per thread, rank-1 updates.
// LDS tiles stored transposed [k][m] / [k][n], padded to 132 floats/row.
// ---------------------------------------------------------------------------
__device__ __forceinline__ void gemm_body(const float* __restrict__ X,
                                          const float* __restrict__ W,
                                          float* __restrict__ Y,
                                          int N, int K, int bm, int bn,
                                          float (*Xs)[132], float (*Ws)[132]) {
    const int tid = threadIdx.x;
    const int tx = tid & 15, ty = tid >> 4;

    float acc[8][8];
#pragma unroll
    for (int i = 0; i < 8; ++i)
#pragma unroll
        for (int j = 0; j < 8; ++j) acc[i][j] = 0.f;

    for (int k0 = 0; k0 < K; k0 += 16) {
#pragma unroll
        for (int p = 0; p < 2; ++p) {
            int f = p * 1024 + tid * 4;
            int row = f >> 4;
            int kk = f & 15;
            float4 xv = *(const float4*)(X + (size_t)(bm + row) * K + k0 + kk);
            Xs[kk + 0][row] = xv.x; Xs[kk + 1][row] = xv.y;
            Xs[kk + 2][row] = xv.z; Xs[kk + 3][row] = xv.w;
            float4 wv = *(const float4*)(W + (size_t)(bn + row) * K + k0 + kk);
            Ws[kk + 0][row] = wv.x; Ws[kk + 1][row] = wv.y;
            Ws[kk + 2][row] = wv.z; Ws[kk + 3][row] = wv.w;
        }
        __syncthreads();
#pragma unroll
        for (int kk = 0; kk < 16; ++kk) {
            float4 a0 = *(const float4*)&Xs[kk][ty * 8];
            float4 a1 = *(const float4*)&Xs[kk][ty * 8 + 4];
            float4 b0 = *(const float4*)&Ws[kk][tx * 8];
            float4 b1 = *(const float4*)&Ws[kk][tx * 8 + 4];
            float av[8] = {a0.x, a0.y, a0.z, a0.w, a1.x, a1.y, a1.z, a1.w};
            float bv[8] = {b0.x, b0.y, b0.z, b0.w, b1.x, b1.y, b1.z, b1.w};
#pragma unroll
            for (int i = 0; i < 8; ++i)
#pragma unroll
                for (int j = 0; j < 8; ++j)
                    acc[i][j] = fmaf(av[i], bv[j], acc[i][j]);
        }
        __syncthreads();
    }
#pragma unroll
    for (int i = 0; i < 8; ++i) {
        float* yp = Y + (size_t)(bm + ty * 8 + i) * N + bn + tx * 8;
        *(float4*)yp       = make_float4(acc[i][0], acc[i][1], acc[i][2], acc[i][3]);
        *(float4*)(yp + 4) = make_float4(acc[i][4], acc[i][5], acc[i][6], acc[i][7]);
    }
}

__global__ __launch_bounds__(256) void sgemm_nt(const float* __restrict__ X,
                                                const float* __restrict__ W,
                                                float* __restrict__ Y,
                                                int N, int K) {
    __shared__ float Xs[16][132];
    __shared__ float Ws[16][132];
    gemm_body(X, W, Y, N, K, blockIdx.y * 128, blockIdx.x * 128, Xs, Ws);
}

// Fused QKV: one grid over N_total = H*D + 2*HKV*D = 3072 columns.
// 2048 and 512 are multiples of 128 so each block maps to exactly one weight.
__global__ __launch_bounds__(256) void qkv_gemm(const float* __restrict__ X,
                                                const float* __restrict__ Wq,
                                                const float* __restrict__ Wk,
                                                const float* __restrict__ Wv,
                                                float* __restrict__ qb,
                                                float* __restrict__ kb,
                                                float* __restrict__ vb) {
    __shared__ float Xs[16][132];
    __shared__ float Ws[16][132];
    int bn0 = blockIdx.x * 128;
    const float* Wsel;
    float* Ysel;
    int bn, Nout;
    if (bn0 < H * D)            { Wsel = Wq; Ysel = qb; bn = bn0;                 Nout = H * D;  }
    else if (bn0 < H*D + HKV*D) { Wsel = Wk; Ysel = kb; bn = bn0 - H * D;         Nout = HKV*D; }
    else                        { Wsel = Wv; Ysel = vb; bn = bn0 - H*D - HKV*D;   Nout = HKV*D; }
    gemm_body(X, Wsel, Ysel, Nout, C, blockIdx.y * 128, bn, Xs, Ws);
}

// ---------------------------------------------------------------------------
// RoPE (interleaved cos/sin). Thread handles dims d and d+32 of one (b,t,h).
// cos/sin index for dim d is (d>>1); for dim d+32 it's (d>>1)+16.
// rotate_half: out[d] = x[d]*c1 - x[d+32]*s1 ; out[d+32] = x[d+32]*c2 + x[d]*s2
// ---------------------------------------------------------------------------
__global__ void rope_kernel(float* __restrict__ buf, const int* __restrict__ pos_ids,
                            int nheads, int total) {
    int idx = blockIdx.x * blockDim.x + threadIdx.x;
    if (idx >= total) return;
    int d = idx & 31;
    int rest = idx >> 5;                 // = (b*T + t)*nheads + h
    int t = (rest / nheads) % T;
    float pos = (float)pos_ids[t];
    int i1 = d >> 1;
    const float NEG_LF = -(2.0f / 64.0f) * 13.287712379549449f; // -2/D * log2(10000)
    float a1 = pos * exp2f(NEG_LF * (float)i1);
    float a2 = pos * exp2f(NEG_LF * (float)(i1 + 16));
    float c1 = cosf(a1), s1 = sinf(a1);
    float c2 = cosf(a2), s2 = sinf(a2);
    size_t base = (size_t)rest * D + d;
    float x1 = buf[base], x2 = buf[base + 32];
    buf[base]      = x1 * c1 - x2 * s1;
    buf[base + 32] = x2 * c2 + x1 * s2;
}

// ---------------------------------------------------------------------------
// fp32 flash attention, causal, GQA (h -> h>>2). 64-query tile per block.
// Online softmax; K/V tiles in LDS; P round-trips through LDS (transposed).
// ---------------------------------------------------------------------------
__global__ __launch_bounds__(256) void flash_attn(const float* __restrict__ Qb,
                                                  const float* __restrict__ Kb,
                                                  const float* __restrict__ Vb,
                                                  float* __restrict__ Yb) {
    __shared__ float Qs[64][64];   // [d][i]
    __shared__ float Ks[64][64];   // [d][j]
    __shared__ float Vs[64][64];   // [j][c]
    __shared__ float Ps[64][68];   // [j][i], padded (68*4B = 16B-aligned rows)
    __shared__ float m_s[64], l_s[64], alpha_s[64];

    const int q0 = blockIdx.x * 64;
    const int h  = blockIdx.y;
    const int b  = blockIdx.z;
    const int hkv = h >> 2;        // rep = H/HKV = 4, repeat_interleave
    const int tid = threadIdx.x;
    const int tx = tid & 15, ty = tid >> 4;

    for (int e = tid; e < 64 * 16; e += 256) {
        int i = e >> 4, d4 = (e & 15) * 4;
        const float* p = Qb + ((size_t)((b * T + q0 + i) * H) + h) * D + d4;
        float4 v = *(const float4*)p;
        Qs[d4 + 0][i] = v.x; Qs[d4 + 1][i] = v.y;
        Qs[d4 + 2][i] = v.z; Qs[d4 + 3][i] = v.w;
    }
    if (tid < 64) { m_s[tid] = -1e30f; l_s[tid] = 0.f; }

    float acc[4][4] = {{0.f}};

    for (int k0 = 0; k0 <= q0; k0 += 64) {
        for (int e = tid; e < 64 * 16; e += 256) {
            int j = e >> 4, d4 = (e & 15) * 4;
            const float* kp = Kb + ((size_t)((b * T + k0 + j) * HKV) + hkv) * D + d4;
            float4 kv = *(const float4*)kp;
            Ks[d4 + 0][j] = kv.x; Ks[d4 + 1][j] = kv.y;
            Ks[d4 + 2][j] = kv.z; Ks[d4 + 3][j] = kv.w;
            const float* vp = Vb + ((size_t)((b * T + k0 + j) * HKV) + hkv) * D + d4;
            *(float4*)&Vs[j][d4] = *(const float4*)vp;
        }
        __syncthreads();

        // S = Q K^T (4x4 per thread, rank-1 over d)
        float s[4][4] = {{0.f}};
#pragma unroll
        for (int kk = 0; kk < 64; ++kk) {
            float4 qv = *(const float4*)&Qs[kk][ty * 4];
            float4 kv = *(const float4*)&Ks[kk][tx * 4];
            float qa[4] = {qv.x, qv.y, qv.z, qv.w};
            float ka[4] = {kv.x, kv.y, kv.z, kv.w};
#pragma unroll
            for (int ii = 0; ii < 4; ++ii)
#pragma unroll
                for (int jj = 0; jj < 4; ++jj)
                    s[ii][jj] = fmaf(qa[ii], ka[jj], s[ii][jj]);
        }
        const bool diag = (k0 == q0);
#pragma unroll
        for (int ii = 0; ii < 4; ++ii)
#pragma unroll
            for (int jj = 0; jj < 4; ++jj) {
                float v = s[ii][jj] * SCALE;
                if (diag && (tx * 4 + jj > ty * 4 + ii)) v = -1e30f;
                Ps[tx * 4 + jj][ty * 4 + ii] = v;
            }
        __syncthreads();

        // online softmax row stats (one thread per query row)
        if (tid < 64) {
            int i = tid;
            float mloc = -1e30f;
            for (int j = 0; j < 64; ++j) mloc = fmaxf(mloc, Ps[j][i]);
            float mold = m_s[i];
            float mnew = fmaxf(mold, mloc);
            float alpha = __expf(mold - mnew);
            float sum = 0.f;
            for (int j = 0; j < 64; ++j) {
                float p = __expf(Ps[j][i] - mnew);
                Ps[j][i] = p;
                sum += p;
            }
            l_s[i] = l_s[i] * alpha + sum;
            m_s[i] = mnew;
            alpha_s[i] = alpha;
        }
        __syncthreads();

        // O = O*alpha + P @ V (rank-1 over j)
        float al[4];
#pragma unroll
        for (int ii = 0; ii < 4; ++ii) al[ii] = alpha_s[ty * 4 + ii];
#pragma unroll
        for (int ii = 0; ii < 4; ++ii)
#pragma unroll
            for (int jj = 0; jj < 4; ++jj) acc[ii][jj] *= al[ii];
#pragma unroll
        for (int j = 0; j < 64; ++j) {
            float4 pv = *(const float4*)&Ps[j][ty * 4];
            float4 vv = *(const float4*)&Vs[j][tx * 4];
            float pa[4] = {pv.x, pv.y, pv.z, pv.w};
            float va[4] = {vv.x, vv.y, vv.z, vv.w};
#pragma unroll
            for (int ii = 0; ii < 4; ++ii)
#pragma unroll
                for (int jj = 0; jj < 4; ++jj)
                    acc[ii][jj] = fmaf(pa[ii], va[jj], acc[ii][jj]);
        }
        __syncthreads();
    }

#pragma unroll
    for (int ii = 0; ii < 4; ++ii) {
        int i = ty * 4 + ii;
        float inv = 1.0f / l_s[i];
        float* yp = Yb + ((size_t)((b * T + q0 + i) * H) + h) * D + tx * 4;
        *(float4*)yp = make_float4(acc[ii][0] * inv, acc[ii][1] * inv,
                                   acc[ii][2] * inv, acc[ii][3] * inv);
    }
}

// ---------------------------------------------------------------------------
extern "C" void kernel_launch(void* const* d_in, const int* in_sizes, int n_in,
                              void* d_out, int out_size, void* d_ws, size_t ws_size,
                              hipStream_t stream) {
    const float* x  = (const float*)d_in[0];
    const float* Wq = (const float*)d_in[1];
    const float* Wk = (const float*)d_in[2];
    const float* Wv = (const float*)d_in[3];
    const float* Wc = (const float*)d_in[4];
    const int*  pos = (const int*)d_in[5];
    float* out = (float*)d_out;

    // workspace layout (floats): q[B,T,H,D] k[B,T,HKV,D] v[B,T,HKV,D] y[B,T,H,D]
    float* qb = (float*)d_ws;
    float* kb = qb + (size_t)B * T * H * D;
    float* vb = kb + (size_t)B * T * HKV * D;
    float* yb = vb + (size_t)B * T * HKV * D;

    // 1) fused QKV projection
    dim3 g1((H * D + 2 * HKV * D) / 128, (B * T) / 128);  // 24 x 32
    qkv_gemm<<<g1, 256, 0, stream>>>(x, Wq, Wk, Wv, qb, kb, vb);

    // 2) RoPE on q and k
    rope_kernel<<<(B * T * H * 32) / 256, 256, 0, stream>>>(qb, pos, H, B * T * H * 32);
    rope_kernel<<<(B * T * HKV * 32) / 256, 256, 0, stream>>>(kb, pos, HKV, B * T * HKV * 32);

    // 3) causal GQA flash attention -> y[B,T,H,D] (== [B,T,C])
    dim3 g2(T / 64, H, B);
    flash_attn<<<g2, 256, 0, stream>>>(qb, kb, vb, yb);

    // 4) output projection
    dim3 g3(C / 128, (B * T) / 128);
    sgemm_nt<<<g3, 256, 0, stream>>>(yb, Wc, out, C, C);
}

// Round 2
// 1330.964 us; speedup vs baseline: 1.7547x; 1.7547x over previous
//
#include <hip/hip_runtime.h>

constexpr int B   = 2;
constexpr int T   = 2048;
constexpr int C   = 2048;
constexpr int H   = 32;
constexpr int HKV = 8;
constexpr int D   = 64;
constexpr float SCALE = 0.125f; // 1/sqrt(64)

typedef __attribute__((ext_vector_type(8))) short bf16x8;
typedef __attribute__((ext_vector_type(4))) float f32x4;

__device__ __forceinline__ unsigned short f2bf(float f) {
    unsigned u = __builtin_bit_cast(unsigned, f);
    u += 0x7fff + ((u >> 16) & 1);          // round-to-nearest-even
    return (unsigned short)(u >> 16);
}

// ---------------------------------------------------------------------------
// fp32 NT SGEMM (unchanged from round 1 — known good)
// ---------------------------------------------------------------------------
__device__ __forceinline__ void gemm_body(const float* __restrict__ X,
                                          const float* __restrict__ W,
                                          float* __restrict__ Y,
                                          int N, int K, int bm, int bn,
                                          float (*Xs)[132], float (*Ws)[132]) {
    const int tid = threadIdx.x;
    const int tx = tid & 15, ty = tid >> 4;

    float acc[8][8];
#pragma unroll
    for (int i = 0; i < 8; ++i)
#pragma unroll
        for (int j = 0; j < 8; ++j) acc[i][j] = 0.f;

    for (int k0 = 0; k0 < K; k0 += 16) {
#pragma unroll
        for (int p = 0; p < 2; ++p) {
            int f = p * 1024 + tid * 4;
            int row = f >> 4;
            int kk = f & 15;
            float4 xv = *(const float4*)(X + (size_t)(bm + row) * K + k0 + kk);
            Xs[kk + 0][row] = xv.x; Xs[kk + 1][row] = xv.y;
            Xs[kk + 2][row] = xv.z; Xs[kk + 3][row] = xv.w;
            float4 wv = *(const float4*)(W + (size_t)(bn + row) * K + k0 + kk);
            Ws[kk + 0][row] = wv.x; Ws[kk + 1][row] = wv.y;
            Ws[kk + 2][row] = wv.z; Ws[kk + 3][row] = wv.w;
        }
        __syncthreads();
#pragma unroll
        for (int kk = 0; kk < 16; ++kk) {
            float4 a0 = *(const float4*)&Xs[kk][ty * 8];
            float4 a1 = *(const float4*)&Xs[kk][ty * 8 + 4];
            float4 b0 = *(const float4*)&Ws[kk][tx * 8];
            float4 b1 = *(const float4*)&Ws[kk][tx * 8 + 4];
            float av[8] = {a0.x, a0.y, a0.z, a0.w, a1.x, a1.y, a1.z, a1.w};
            float bv[8] = {b0.x, b0.y, b0.z, b0.w, b1.x, b1.y, b1.z, b1.w};
#pragma unroll
            for (int i = 0; i < 8; ++i)
#pragma unroll
                for (int j = 0; j < 8; ++j)
                    acc[i][j] = fmaf(av[i], bv[j], acc[i][j]);
        }
        __syncthreads();
    }
#pragma unroll
    for (int i = 0; i < 8; ++i) {
        float* yp = Y + (size_t)(bm + ty * 8 + i) * N + bn + tx * 8;
        *(float4*)yp       = make_float4(acc[i][0], acc[i][1], acc[i][2], acc[i][3]);
        *(float4*)(yp + 4) = make_float4(acc[i][4], acc[i][5], acc[i][6], acc[i][7]);
    }
}

__global__ __launch_bounds__(256) void sgemm_nt(const float* __restrict__ X,
                                                const float* __restrict__ W,
                                                float* __restrict__ Y,
                                                int N, int K) {
    __shared__ float Xs[16][132];
    __shared__ float Ws[16][132];
    gemm_body(X, W, Y, N, K, blockIdx.y * 128, blockIdx.x * 128, Xs, Ws);
}

__global__ __launch_bounds__(256) void qkv_gemm(const float* __restrict__ X,
                                                const float* __restrict__ Wq,
                                                const float* __restrict__ Wk,
                                                const float* __restrict__ Wv,
                                                float* __restrict__ qb,
                                                float* __restrict__ kb,
                                                float* __restrict__ vb) {
    __shared__ float Xs[16][132];
    __shared__ float Ws[16][132];
    int bn0 = blockIdx.x * 128;
    const float* Wsel;
    float* Ysel;
    int bn, Nout;
    if (bn0 < H * D)            { Wsel = Wq; Ysel = qb; bn = bn0;                 Nout = H * D;  }
    else if (bn0 < H*D + HKV*D) { Wsel = Wk; Ysel = kb; bn = bn0 - H * D;         Nout = HKV*D; }
    else                        { Wsel = Wv; Ysel = vb; bn = bn0 - H*D - HKV*D;   Nout = HKV*D; }
    gemm_body(X, Wsel, Ysel, Nout, C, blockIdx.y * 128, bn, Xs, Ws);
}

// ---------------------------------------------------------------------------
// RoPE + cast fp32 -> bf16. Thread handles dims d and d+32 of one (b,t,h).
// ---------------------------------------------------------------------------
__global__ void rope_cast(const float* __restrict__ in, unsigned short* __restrict__ out,
                          const int* __restrict__ pos_ids, int nheads, int total) {
    int idx = blockIdx.x * blockDim.x + threadIdx.x;
    if (idx >= total) return;
    int d = idx & 31;
    int rest = idx >> 5;                 // = (b*T + t)*nheads + h
    int t = (rest / nheads) % T;
    float pos = (float)pos_ids[t];
    int i1 = d >> 1;
    const float NEG_LF = -(2.0f / 64.0f) * 13.287712379549449f; // -2/D * log2(10000)
    float a1 = pos * exp2f(NEG_LF * (float)i1);
    float a2 = pos * exp2f(NEG_LF * (float)(i1 + 16));
    float c1 = cosf(a1), s1 = sinf(a1);
    float c2 = cosf(a2), s2 = sinf(a2);
    size_t base = (size_t)rest * D + d;
    float x1 = in[base], x2 = in[base + 32];
    out[base]      = f2bf(x1 * c1 - x2 * s1);
    out[base + 32] = f2bf(x2 * c2 + x1 * s2);
}

// ---------------------------------------------------------------------------
// V cast fp32 -> bf16 with transpose to [b][hkv][d][t] so the attention
// kernel can stage V^T tiles with coalesced, conflict-free loads.
// ---------------------------------------------------------------------------
__global__ __launch_bounds__(256) void vcast_transpose(const float* __restrict__ vb,
                                                       unsigned short* __restrict__ vtg) {
    __shared__ unsigned short Vs[64][72];
    const int t0 = blockIdx.x * 64;
    const int hkv = blockIdx.y;
    const int b = blockIdx.z;
    const int tid = threadIdx.x;

    for (int e = tid; e < 64 * 16; e += 256) {
        int t = e >> 4, d4 = (e & 15) * 4;
        float4 v = *(const float4*)(vb + ((size_t)((b * T + t0 + t) * HKV) + hkv) * D + d4);
        Vs[d4 + 0][t] = f2bf(v.x);
        Vs[d4 + 1][t] = f2bf(v.y);
        Vs[d4 + 2][t] = f2bf(v.z);
        Vs[d4 + 3][t] = f2bf(v.w);
    }
    __syncthreads();
    for (int e = tid; e < 512; e += 256) {
        int d = e >> 3, c = e & 7;
        uint4 val = *(const uint4*)&Vs[d][c * 8];
        *(uint4*)(vtg + ((size_t)((b * HKV + hkv) * D) + d) * T + t0 + c * 8) = val;
    }
}

// ---------------------------------------------------------------------------
// bf16 MFMA flash attention, causal, GQA. 64-query tile / block, 4 waves,
// each wave owns a 16-query strip. 16x16x32 MFMA.
// A layout: A[m=lane&15][k=quad*8+j]; B layout: B[k=quad*8+j][n=lane&15];
// C/D layout: col=lane&15, row=quad*4+reg.
// ---------------------------------------------------------------------------
__global__ __launch_bounds__(256) void flash_attn_mfma(const unsigned short* __restrict__ Qh,
                                                       const unsigned short* __restrict__ Kh,
                                                       const unsigned short* __restrict__ Vtg,
                                                       float* __restrict__ Yb) {
    __shared__ unsigned short Ks[64][72];      // [key j][d], 144B rows (bank shift 4/row)
    __shared__ unsigned short Vt[64][72];      // [d][key j]
    __shared__ unsigned short Ps[4][16][72];   // per-wave P strip [i][j]

    const int q0 = blockIdx.x * 64;
    const int h  = blockIdx.y;
    const int b  = blockIdx.z;
    const int hkv = h >> 2;
    const int tid = threadIdx.x;
    const int wave = tid >> 6;
    const int lane = tid & 63;
    const int m = lane & 15;          // col within 16-tile
    const int quad = lane >> 4;

    // Q A-frags for this wave's 16 rows (resident in regs for whole kernel)
    const unsigned short* qrow = Qh + ((size_t)((b * T + q0 + wave * 16 + m) * H) + h) * D;
    bf16x8 qa0 = *(const bf16x8*)(qrow + quad * 8);       // k = 0..31
    bf16x8 qa1 = *(const bf16x8*)(qrow + 32 + quad * 8);  // k = 32..63

    f32x4 o[4];
#pragma unroll
    for (int dt = 0; dt < 4; ++dt) o[dt] = (f32x4){0.f, 0.f, 0.f, 0.f};
    float mrow[4] = {-1e30f, -1e30f, -1e30f, -1e30f};
    float lrow[4] = {0.f, 0.f, 0.f, 0.f};

    const size_t kbase = ((size_t)(b * T) * HKV + hkv) * D;                // + (k0+row)*HKV*D
    const size_t vbase = ((size_t)(b * HKV + hkv) * D) * (size_t)T;        // + d*T + t

    for (int k0 = 0; k0 <= q0; k0 += 64) {
        // ---- stage K tile [64][64] and V^T tile [64][64] (coalesced uint4) ----
        for (int e = tid; e < 512; e += 256) {
            int row = e >> 3, c = e & 7;
            *(uint4*)&Ks[row][c * 8] =
                *(const uint4*)(Kh + kbase + (size_t)(k0 + row) * (HKV * D) + c * 8);
            *(uint4*)&Vt[row][c * 8] =
                *(const uint4*)(Vtg + vbase + (size_t)row * T + k0 + c * 8);
        }
        __syncthreads();

        // ---- S = Q K^T : 4 n-tiles of 16 keys ----
        const bool diagblk = (k0 == q0);
        f32x4 s[4];
#pragma unroll
        for (int nt = 0; nt < 4; ++nt) {
            if (diagblk && nt > wave) {               // wave-uniform: fully masked
                s[nt] = (f32x4){-1e30f, -1e30f, -1e30f, -1e30f};
                continue;
            }
            bf16x8 kb0 = *(const bf16x8*)&Ks[nt * 16 + m][quad * 8];
            bf16x8 kb1 = *(const bf16x8*)&Ks[nt * 16 + m][32 + quad * 8];
            f32x4 acc = (f32x4){0.f, 0.f, 0.f, 0.f};
            acc = __builtin_amdgcn_mfma_f32_16x16x32_bf16(qa0, kb0, acc, 0, 0, 0);
            acc = __builtin_amdgcn_mfma_f32_16x16x32_bf16(qa1, kb1, acc, 0, 0, 0);
            acc *= SCALE;
            if (diagblk && nt == wave) {              // diagonal 16x16: elementwise mask
#pragma unroll
                for (int r = 0; r < 4; ++r)
                    if (m > quad * 4 + r) acc[r] = -1e30f;
            }
            s[nt] = acc;
        }

        // ---- online softmax (per row r; 16-lane butterfly within quad group) ----
        float alpha[4];
#pragma unroll
        for (int r = 0; r < 4; ++r) {
            float mx = fmaxf(fmaxf(s[0][r], s[1][r]), fmaxf(s[2][r], s[3][r]));
            mx = fmaxf(mx, __shfl_xor(mx, 1));
            mx = fmaxf(mx, __shfl_xor(mx, 2));
            mx = fmaxf(mx, __shfl_xor(mx, 4));
            mx = fmaxf(mx, __shfl_xor(mx, 8));
            float mnew = fmaxf(mrow[r], mx);
            alpha[r] = __expf(mrow[r] - mnew);
            mrow[r] = mnew;
            float psum = 0.f;
#pragma unroll
            for (int nt = 0; nt < 4; ++nt) {
                float p = __expf(s[nt][r] - mnew);
                s[nt][r] = p;
                psum += p;
            }
            psum += __shfl_xor(psum, 1);
            psum += __shfl_xor(psum, 2);
            psum += __shfl_xor(psum, 4);
            psum += __shfl_xor(psum, 8);
            lrow[r] = lrow[r] * alpha[r] + psum;
        }

        // ---- P (C-layout) -> wave-private LDS strip -> A-layout frags ----
#pragma unroll
        for (int nt = 0; nt < 4; ++nt)
#pragma unroll
            for (int r = 0; r < 4; ++r)
                Ps[wave][quad * 4 + r][nt * 16 + m] = f2bf(s[nt][r]);

        // rescale O by alpha (row r of each d-tile)
#pragma unroll
        for (int dt = 0; dt < 4; ++dt)
#pragma unroll
            for (int r = 0; r < 4; ++r) o[dt][r] *= alpha[r];

        bf16x8 pa0 = *(const bf16x8*)&Ps[wave][m][quad * 8];       // j = 0..31
        bf16x8 pa1 = *(const bf16x8*)&Ps[wave][m][32 + quad * 8];  // j = 32..63
#pragma unroll
        for (int dt = 0; dt < 4; ++dt) {
            bf16x8 vb0 = *(const bf16x8*)&Vt[dt * 16 + m][quad * 8];
            bf16x8 vb1 = *(const bf16x8*)&Vt[dt * 16 + m][32 + quad * 8];
            o[dt] = __builtin_amdgcn_mfma_f32_16x16x32_bf16(pa0, vb0, o[dt], 0, 0, 0);
            o[dt] = __builtin_amdgcn_mfma_f32_16x16x32_bf16(pa1, vb1, o[dt], 0, 0, 0);
        }
        __syncthreads();   // protect Ks/Vt before restage
    }

    // ---- epilogue: O / l -> y[b][t][h][d] fp32 ----
#pragma unroll
    for (int r = 0; r < 4; ++r) {
        float inv = 1.0f / lrow[r];
        int trow = q0 + wave * 16 + quad * 4 + r;
        float* yp = Yb + ((size_t)(b * T + trow) * H + h) * D;
#pragma unroll
        for (int dt = 0; dt < 4; ++dt)
            yp[dt * 16 + m] = o[dt][r] * inv;
    }
}

// ---------------------------------------------------------------------------
extern "C" void kernel_launch(void* const* d_in, const int* in_sizes, int n_in,
                              void* d_out, int out_size, void* d_ws, size_t ws_size,
                              hipStream_t stream) {
    const float* x  = (const float*)d_in[0];
    const float* Wq = (const float*)d_in[1];
    const float* Wk = (const float*)d_in[2];
    const float* Wv = (const float*)d_in[3];
    const float* Wc = (const float*)d_in[4];
    const int*  pos = (const int*)d_in[5];
    float* out = (float*)d_out;

    // workspace: qb[8.4M f32] kb[2.1M f32] vb[2.1M f32] qh[8.4M bf16] kh[2.1M bf16] vtg[2.1M bf16]
    // yb aliases qb (qb dead after rope_cast).
    float* qb = (float*)d_ws;
    float* kb = qb + (size_t)B * T * H * D;
    float* vb = kb + (size_t)B * T * HKV * D;
    unsigned short* qh  = (unsigned short*)(vb + (size_t)B * T * HKV * D);
    unsigned short* kh  = qh + (size_t)B * T * H * D;
    unsigned short* vtg = kh + (size_t)B * T * HKV * D;
    float* yb = qb;

    // 1) fused QKV projection (fp32)
    dim3 g1((H * D + 2 * HKV * D) / 128, (B * T) / 128);
    qkv_gemm<<<g1, 256, 0, stream>>>(x, Wq, Wk, Wv, qb, kb, vb);

    // 2) RoPE+cast q,k -> bf16; cast+transpose v -> bf16 [b][hkv][d][t]
    rope_cast<<<(B * T * H * 32) / 256, 256, 0, stream>>>(qb, qh, pos, H, B * T * H * 32);
    rope_cast<<<(B * T * HKV * 32) / 256, 256, 0, stream>>>(kb, kh, pos, HKV, B * T * HKV * 32);
    vcast_transpose<<<dim3(T / 64, HKV, B), 256, 0, stream>>>(vb, vtg);

    // 3) causal GQA flash attention (bf16 MFMA) -> yb fp32 [B,T,C]
    dim3 g2(T / 64, H, B);
    flash_attn_mfma<<<g2, 256, 0, stream>>>(qh, kh, vtg, yb);

    // 4) output projection (fp32)
    dim3 g3(C / 128, (B * T) / 128);
    sgemm_nt<<<g3, 256, 0, stream>>>(yb, Wc, out, C, C);
}

// Round 3
// 479.082 us; speedup vs baseline: 4.8748x; 2.7782x over previous
//
#include <hip/hip_runtime.h>

constexpr int B   = 2;
constexpr int T   = 2048;
constexpr int C   = 2048;
constexpr int H   = 32;
constexpr int HKV = 8;
constexpr int D   = 64;
constexpr float SCALE = 0.125f; // 1/sqrt(64)

typedef __attribute__((ext_vector_type(8))) short bf16x8;
typedef __attribute__((ext_vector_type(4))) float f32x4;

__device__ __forceinline__ unsigned short f2bf(float f) {
    unsigned u = __builtin_bit_cast(unsigned, f);
    u += 0x7fff + ((u >> 16) & 1);          // round-to-nearest-even
    return (unsigned short)(u >> 16);
}
__device__ __forceinline__ float bf2f(unsigned short u) {
    unsigned v = (unsigned)u << 16;
    return __builtin_bit_cast(float, v);
}

typedef __attribute__((address_space(1))) const unsigned char ga_t;
typedef __attribute__((address_space(3))) unsigned char lds_t;
__device__ __forceinline__ void gl2lds16(const void* g, void* l) {
    // 16B per lane, dest = wave-uniform base + lane*16
    __builtin_amdgcn_global_load_lds((ga_t*)g, (lds_t*)l, 16, 0, 0);
}

// ---------------------------------------------------------------------------
// fp32 -> bf16 cast, 8 elems/thread (n must be a multiple of 8)
// ---------------------------------------------------------------------------
__global__ __launch_bounds__(256) void cast_bf16(const float* __restrict__ in,
                                                 unsigned short* __restrict__ out, int n) {
    int i = (blockIdx.x * blockDim.x + threadIdx.x) * 8;
    if (i >= n) return;
    float4 a = *(const float4*)(in + i);
    float4 b = *(const float4*)(in + i + 4);
    uint4 r;
    r.x = (unsigned)f2bf(a.x) | ((unsigned)f2bf(a.y) << 16);
    r.y = (unsigned)f2bf(a.z) | ((unsigned)f2bf(a.w) << 16);
    r.z = (unsigned)f2bf(b.x) | ((unsigned)f2bf(b.y) << 16);
    r.w = (unsigned)f2bf(b.z) | ((unsigned)f2bf(b.w) << 16);
    *(uint4*)(out + i) = r;
}

// ---------------------------------------------------------------------------
// bf16 MFMA NT GEMM: Y[m][n] = sum_k X[m][k]*W[n][k].
// 128x128 tile, BK=32, 256 threads = 4 waves (2x2), 4x4 16x16x32 tiles/wave.
// global_load_lds width=16 staging; LDS chunk-XOR swizzle (applied to the
// global source address since LDS dest is lane-contiguous by construction).
// ---------------------------------------------------------------------------
template <typename OutT>
__device__ __forceinline__ void gemm_mfma_body(const unsigned short* __restrict__ Xh,
                                               const unsigned short* __restrict__ Wh,
                                               OutT* __restrict__ Y,
                                               int Nloc, int K, int bm, int bn) {
    __shared__ __align__(16) unsigned short As[128 * 32];
    __shared__ __align__(16) unsigned short Bs[128 * 32];
    char* AsB = (char*)As;
    char* BsB = (char*)Bs;

    const int tid  = threadIdx.x;
    const int wave = tid >> 6, lane = tid & 63;
    const int wm = (wave >> 1) * 64, wn = (wave & 1) * 64;
    const int m = lane & 15, quad = lane >> 4;

    // staging: thread t -> LDS slot t (16B); row r0 = t>>2, slot-chunk cs = t&3.
    // element stored at slot (r, cs) is global k-chunk cs ^ (r&3).
    const int r0 = tid >> 2;
    const int cs = tid & 3;
    const int cg = cs ^ (r0 & 3);
    const int wbase = (tid & 192) * 16;     // wave*1024, wave-uniform

    const unsigned short* gA = Xh + (size_t)(bm + r0) * K + cg * 8;
    const unsigned short* gB = Wh + (size_t)(bn + r0) * K + cg * 8;
    const size_t rowStep64 = (size_t)64 * K;

    // ds_read offsets (bytes), swizzle-matched: chunk quad of row ra is at
    // slot-chunk quad ^ (ra&3)
    int aoff[4], boff[4];
#pragma unroll
    for (int mt = 0; mt < 4; ++mt) {
        int ra = wm + mt * 16 + m;
        aoff[mt] = ra * 64 + ((quad ^ (ra & 3)) * 16);
        int rb = wn + mt * 16 + m;
        boff[mt] = rb * 64 + ((quad ^ (rb & 3)) * 16);
    }

    f32x4 acc[4][4];
#pragma unroll
    for (int i = 0; i < 4; ++i)
#pragma unroll
        for (int j = 0; j < 4; ++j) acc[i][j] = (f32x4){0.f, 0.f, 0.f, 0.f};

    for (int k0 = 0; k0 < K; k0 += 32) {
        gl2lds16(gA,             AsB + wbase);
        gl2lds16(gA + rowStep64, AsB + 4096 + wbase);
        gl2lds16(gB,             BsB + wbase);
        gl2lds16(gB + rowStep64, BsB + 4096 + wbase);
        gA += 32;
        gB += 32;
        __syncthreads();

        bf16x8 af[4], bfr[4];
#pragma unroll
        for (int mt = 0; mt < 4; ++mt) af[mt]  = *(const bf16x8*)(AsB + aoff[mt]);
#pragma unroll
        for (int nt = 0; nt < 4; ++nt) bfr[nt] = *(const bf16x8*)(BsB + boff[nt]);
#pragma unroll
        for (int mt = 0; mt < 4; ++mt)
#pragma unroll
            for (int nt = 0; nt < 4; ++nt)
                acc[mt][nt] = __builtin_amdgcn_mfma_f32_16x16x32_bf16(af[mt], bfr[nt],
                                                                      acc[mt][nt], 0, 0, 0);
        __syncthreads();
    }

    // epilogue: C/D layout col=lane&15, row=quad*4+reg
#pragma unroll
    for (int mt = 0; mt < 4; ++mt)
#pragma unroll
        for (int r = 0; r < 4; ++r) {
            size_t row = (size_t)(bm + wm + mt * 16 + quad * 4 + r);
#pragma unroll
            for (int nt = 0; nt < 4; ++nt) {
                int col = bn + wn + nt * 16 + m;
                float v = acc[mt][nt][r];
                if constexpr (sizeof(OutT) == 2)
                    Y[row * Nloc + col] = f2bf(v);
                else
                    Y[row * Nloc + col] = v;
            }
        }
}

// Fused QKV (bf16 out, pre-RoPE): columns [0,2048)->q, [2048,2560)->k, [2560,3072)->v
__global__ __launch_bounds__(256) void qkv_gemm_bf16(const unsigned short* __restrict__ Xh,
                                                     const unsigned short* __restrict__ Wqh,
                                                     const unsigned short* __restrict__ Wkh,
                                                     const unsigned short* __restrict__ Wvh,
                                                     unsigned short* __restrict__ qh,
                                                     unsigned short* __restrict__ kh,
                                                     unsigned short* __restrict__ vh) {
    int bn0 = blockIdx.x * 128;
    const unsigned short* Wsel;
    unsigned short* Ysel;
    int bnl, Nloc;
    if (bn0 < H * D)                { Wsel = Wqh; Ysel = qh; bnl = bn0;                  Nloc = H * D;   }
    else if (bn0 < H*D + HKV*D)     { Wsel = Wkh; Ysel = kh; bnl = bn0 - H * D;          Nloc = HKV * D; }
    else                            { Wsel = Wvh; Ysel = vh; bnl = bn0 - H*D - HKV*D;    Nloc = HKV * D; }
    gemm_mfma_body<unsigned short>(Xh, Wsel, Ysel, Nloc, C, blockIdx.y * 128, bnl);
}

// Output projection (fp32 out)
__global__ __launch_bounds__(256) void out_gemm_bf16(const unsigned short* __restrict__ Xh,
                                                     const unsigned short* __restrict__ Wh,
                                                     float* __restrict__ Y) {
    gemm_mfma_body<float>(Xh, Wh, Y, C, C, blockIdx.y * 128, blockIdx.x * 128);
}

// ---------------------------------------------------------------------------
// RoPE in-place on bf16 (interleaved cos/sin; pairs d, d+32)
// ---------------------------------------------------------------------------
__global__ void rope_bf16(unsigned short* __restrict__ buf, const int* __restrict__ pos_ids,
                          int nheads, int total) {
    int idx = blockIdx.x * blockDim.x + threadIdx.x;
    if (idx >= total) return;
    int d = idx & 31;
    int rest = idx >> 5;                 // = (b*T + t)*nheads + h
    int t = (rest / nheads) % T;
    float pos = (float)pos_ids[t];
    int i1 = d >> 1;
    const float NEG_LF = -(2.0f / 64.0f) * 13.287712379549449f; // -2/D * log2(10000)
    float a1 = pos * exp2f(NEG_LF * (float)i1);
    float a2 = pos * exp2f(NEG_LF * (float)(i1 + 16));
    float c1 = cosf(a1), s1 = sinf(a1);
    float c2 = cosf(a2), s2 = sinf(a2);
    size_t base = (size_t)rest * D + d;
    float x1 = bf2f(buf[base]), x2 = bf2f(buf[base + 32]);
    buf[base]      = f2bf(x1 * c1 - x2 * s1);
    buf[base + 32] = f2bf(x2 * c2 + x1 * s2);
}

// ---------------------------------------------------------------------------
// V transpose bf16 [b][t][hkv][d] -> [b][hkv][d][t]
// ---------------------------------------------------------------------------
__global__ __launch_bounds__(256) void v_transpose(const unsigned short* __restrict__ vh,
                                                   unsigned short* __restrict__ vtg) {
    __shared__ unsigned short Vs[64][72];
    const int t0 = blockIdx.x * 64;
    const int hkv = blockIdx.y;
    const int b = blockIdx.z;
    const int tid = threadIdx.x;

    for (int e = tid; e < 512; e += 256) {
        int t = e >> 3, d8 = (e & 7) * 8;
        uint4 val = *(const uint4*)(vh + ((size_t)((b * T + t0 + t) * HKV) + hkv) * D + d8);
        unsigned short tmp[8];
        *(uint4*)tmp = val;
#pragma unroll
        for (int i = 0; i < 8; ++i) Vs[d8 + i][t] = tmp[i];
    }
    __syncthreads();
    for (int e = tid; e < 512; e += 256) {
        int d = e >> 3, c = e & 7;
        *(uint4*)(vtg + ((size_t)((b * HKV + hkv) * D) + d) * T + t0 + c * 8) =
            *(const uint4*)&Vs[d][c * 8];
    }
}

// ---------------------------------------------------------------------------
// bf16 MFMA flash attention (unchanged core from round 2), bf16 output
// ---------------------------------------------------------------------------
__global__ __launch_bounds__(256) void flash_attn_mfma(const unsigned short* __restrict__ Qh,
                                                       const unsigned short* __restrict__ Kh,
                                                       const unsigned short* __restrict__ Vtg,
                                                       unsigned short* __restrict__ Yh) {
    __shared__ unsigned short Ks[64][72];      // [key j][d]
    __shared__ unsigned short Vt[64][72];      // [d][key j]
    __shared__ unsigned short Ps[4][16][72];   // per-wave P strip [i][j]

    const int q0 = blockIdx.x * 64;
    const int h  = blockIdx.y;
    const int b  = blockIdx.z;
    const int hkv = h >> 2;
    const int tid = threadIdx.x;
    const int wave = tid >> 6;
    const int lane = tid & 63;
    const int m = lane & 15;
    const int quad = lane >> 4;

    const unsigned short* qrow = Qh + ((size_t)((b * T + q0 + wave * 16 + m) * H) + h) * D;
    bf16x8 qa0 = *(const bf16x8*)(qrow + quad * 8);
    bf16x8 qa1 = *(const bf16x8*)(qrow + 32 + quad * 8);

    f32x4 o[4];
#pragma unroll
    for (int dt = 0; dt < 4; ++dt) o[dt] = (f32x4){0.f, 0.f, 0.f, 0.f};
    float mrow[4] = {-1e30f, -1e30f, -1e30f, -1e30f};
    float lrow[4] = {0.f, 0.f, 0.f, 0.f};

    const size_t kbase = ((size_t)(b * T) * HKV + hkv) * D;
    const size_t vbase = ((size_t)(b * HKV + hkv) * D) * (size_t)T;

    for (int k0 = 0; k0 <= q0; k0 += 64) {
        for (int e = tid; e < 512; e += 256) {
            int row = e >> 3, c = e & 7;
            *(uint4*)&Ks[row][c * 8] =
                *(const uint4*)(Kh + kbase + (size_t)(k0 + row) * (HKV * D) + c * 8);
            *(uint4*)&Vt[row][c * 8] =
                *(const uint4*)(Vtg + vbase + (size_t)row * T + k0 + c * 8);
        }
        __syncthreads();

        const bool diagblk = (k0 == q0);
        f32x4 s[4];
#pragma unroll
        for (int nt = 0; nt < 4; ++nt) {
            if (diagblk && nt > wave) {
                s[nt] = (f32x4){-1e30f, -1e30f, -1e30f, -1e30f};
                continue;
            }
            bf16x8 kb0 = *(const bf16x8*)&Ks[nt * 16 + m][quad * 8];
            bf16x8 kb1 = *(const bf16x8*)&Ks[nt * 16 + m][32 + quad * 8];
            f32x4 acc = (f32x4){0.f, 0.f, 0.f, 0.f};
            acc = __builtin_amdgcn_mfma_f32_16x16x32_bf16(qa0, kb0, acc, 0, 0, 0);
            acc = __builtin_amdgcn_mfma_f32_16x16x32_bf16(qa1, kb1, acc, 0, 0, 0);
            acc *= SCALE;
            if (diagblk && nt == wave) {
#pragma unroll
                for (int r = 0; r < 4; ++r)
                    if (m > quad * 4 + r) acc[r] = -1e30f;
            }
            s[nt] = acc;
        }

        float alpha[4];
#pragma unroll
        for (int r = 0; r < 4; ++r) {
            float mx = fmaxf(fmaxf(s[0][r], s[1][r]), fmaxf(s[2][r], s[3][r]));
            mx = fmaxf(mx, __shfl_xor(mx, 1));
            mx = fmaxf(mx, __shfl_xor(mx, 2));
            mx = fmaxf(mx, __shfl_xor(mx, 4));
            mx = fmaxf(mx, __shfl_xor(mx, 8));
            float mnew = fmaxf(mrow[r], mx);
            alpha[r] = __expf(mrow[r] - mnew);
            mrow[r] = mnew;
            float psum = 0.f;
#pragma unroll
            for (int nt = 0; nt < 4; ++nt) {
                float p = __expf(s[nt][r] - mnew);
                s[nt][r] = p;
                psum += p;
            }
            psum += __shfl_xor(psum, 1);
            psum += __shfl_xor(psum, 2);
            psum += __shfl_xor(psum, 4);
            psum += __shfl_xor(psum, 8);
            lrow[r] = lrow[r] * alpha[r] + psum;
        }

#pragma unroll
        for (int nt = 0; nt < 4; ++nt)
#pragma unroll
            for (int r = 0; r < 4; ++r)
                Ps[wave][quad * 4 + r][nt * 16 + m] = f2bf(s[nt][r]);

#pragma unroll
        for (int dt = 0; dt < 4; ++dt)
#pragma unroll
            for (int r = 0; r < 4; ++r) o[dt][r] *= alpha[r];

        bf16x8 pa0 = *(const bf16x8*)&Ps[wave][m][quad * 8];
        bf16x8 pa1 = *(const bf16x8*)&Ps[wave][m][32 + quad * 8];
#pragma unroll
        for (int dt = 0; dt < 4; ++dt) {
            bf16x8 vb0 = *(const bf16x8*)&Vt[dt * 16 + m][quad * 8];
            bf16x8 vb1 = *(const bf16x8*)&Vt[dt * 16 + m][32 + quad * 8];
            o[dt] = __builtin_amdgcn_mfma_f32_16x16x32_bf16(pa0, vb0, o[dt], 0, 0, 0);
            o[dt] = __builtin_amdgcn_mfma_f32_16x16x32_bf16(pa1, vb1, o[dt], 0, 0, 0);
        }
        __syncthreads();
    }

#pragma unroll
    for (int r = 0; r < 4; ++r) {
        float inv = 1.0f / lrow[r];
        int trow = q0 + wave * 16 + quad * 4 + r;
        unsigned short* yp = Yh + ((size_t)(b * T + trow) * H + h) * D;
#pragma unroll
        for (int dt = 0; dt < 4; ++dt)
            yp[dt * 16 + m] = f2bf(o[dt][r] * inv);
    }
}

// ---------------------------------------------------------------------------
extern "C" void kernel_launch(void* const* d_in, const int* in_sizes, int n_in,
                              void* d_out, int out_size, void* d_ws, size_t ws_size,
                              hipStream_t stream) {
    const float* x  = (const float*)d_in[0];
    const float* Wq = (const float*)d_in[1];
    const float* Wk = (const float*)d_in[2];
    const float* Wv = (const float*)d_in[3];
    const float* Wc = (const float*)d_in[4];
    const int*  pos = (const int*)d_in[5];
    float* out = (float*)d_out;

    // bf16 workspace (elements). yh aliases xh (xh dead after qkv_gemm).
    unsigned short* xh  = (unsigned short*)d_ws;           // 8,388,608
    unsigned short* wqh = xh  + (size_t)B * T * C;         // 4,194,304
    unsigned short* wkh = wqh + (size_t)H * D * C;         // 1,048,576
    unsigned short* wvh = wkh + (size_t)HKV * D * C;       // 1,048,576
    unsigned short* wch = wvh + (size_t)HKV * D * C;       // 4,194,304
    unsigned short* qh  = wch + (size_t)C * C;             // 8,388,608
    unsigned short* kh  = qh  + (size_t)B * T * H * D;     // 2,097,152
    unsigned short* vh  = kh  + (size_t)B * T * HKV * D;   // 2,097,152
    unsigned short* vtg = vh  + (size_t)B * T * HKV * D;   // 2,097,152
    unsigned short* yh  = xh;                              // alias

    // 1) casts fp32 -> bf16
    cast_bf16<<<(B * T * C) / (256 * 8), 256, 0, stream>>>(x, xh, B * T * C);
    cast_bf16<<<(H * D * C) / (256 * 8), 256, 0, stream>>>(Wq, wqh, H * D * C);
    cast_bf16<<<(HKV * D * C) / (256 * 8), 256, 0, stream>>>(Wk, wkh, HKV * D * C);
    cast_bf16<<<(HKV * D * C) / (256 * 8), 256, 0, stream>>>(Wv, wvh, HKV * D * C);
    cast_bf16<<<(C * C) / (256 * 8), 256, 0, stream>>>(Wc, wch, C * C);

    // 2) fused QKV projection (bf16 MFMA) -> qh/kh/vh bf16
    dim3 g1((H * D + 2 * HKV * D) / 128, (B * T) / 128);
    qkv_gemm_bf16<<<g1, 256, 0, stream>>>(xh, wqh, wkh, wvh, qh, kh, vh);

    // 3) RoPE in-place on qh, kh; V transpose to [b][hkv][d][t]
    rope_bf16<<<(B * T * H * 32) / 256, 256, 0, stream>>>(qh, pos, H, B * T * H * 32);
    rope_bf16<<<(B * T * HKV * 32) / 256, 256, 0, stream>>>(kh, pos, HKV, B * T * HKV * 32);
    v_transpose<<<dim3(T / 64, HKV, B), 256, 0, stream>>>(vh, vtg);

    // 4) causal GQA flash attention (bf16 MFMA) -> yh bf16
    dim3 g2(T / 64, H, B);
    flash_attn_mfma<<<g2, 256, 0, stream>>>(qh, kh, vtg, yh);

    // 5) output projection (bf16 MFMA, fp32 out)
    dim3 g3(C / 128, (B * T) / 128);
    out_gemm_bf16<<<g3, 256, 0, stream>>>(yh, wch, out);
}

// Round 5
// 416.194 us; speedup vs baseline: 5.6113x; 1.1511x over previous
//
#include <hip/hip_runtime.h>

constexpr int B   = 2;
constexpr int T   = 2048;
constexpr int C   = 2048;
constexpr int H   = 32;
constexpr int HKV = 8;
constexpr int D   = 64;
constexpr float SCALE = 0.125f; // 1/sqrt(64)

typedef __attribute__((ext_vector_type(8))) short bf16x8;
typedef __attribute__((ext_vector_type(4))) float f32x4;

__device__ __forceinline__ unsigned short f2bf(float f) {
    unsigned u = __builtin_bit_cast(unsigned, f);
    u += 0x7fff + ((u >> 16) & 1);          // round-to-nearest-even
    return (unsigned short)(u >> 16);
}
__device__ __forceinline__ float bf2f(unsigned short u) {
    unsigned v = (unsigned)u << 16;
    return __builtin_bit_cast(float, v);
}

typedef __attribute__((address_space(1))) const unsigned char ga_t;
typedef __attribute__((address_space(3))) unsigned char lds_t;
__device__ __forceinline__ void gl2lds16(const void* g, void* l) {
    // 16B per lane, dest = wave-uniform base + lane*16
    __builtin_amdgcn_global_load_lds((ga_t*)g, (lds_t*)l, 16, 0, 0);
}

// ---------------------------------------------------------------------------
// fp32 -> bf16 cast, 8 elems/thread
// ---------------------------------------------------------------------------
__global__ __launch_bounds__(256) void cast_bf16(const float* __restrict__ in,
                                                 unsigned short* __restrict__ out, int n) {
    int i = (blockIdx.x * blockDim.x + threadIdx.x) * 8;
    if (i >= n) return;
    float4 a = *(const float4*)(in + i);
    float4 b = *(const float4*)(in + i + 4);
    uint4 r;
    r.x = (unsigned)f2bf(a.x) | ((unsigned)f2bf(a.y) << 16);
    r.y = (unsigned)f2bf(a.z) | ((unsigned)f2bf(a.w) << 16);
    r.z = (unsigned)f2bf(b.x) | ((unsigned)f2bf(b.y) << 16);
    r.w = (unsigned)f2bf(b.z) | ((unsigned)f2bf(b.w) << 16);
    *(uint4*)(out + i) = r;
}

// ---------------------------------------------------------------------------
// bf16 MFMA NT GEMM (round-3 proven)
// ---------------------------------------------------------------------------
template <typename OutT>
__device__ __forceinline__ void gemm_mfma_body(const unsigned short* __restrict__ Xh,
                                               const unsigned short* __restrict__ Wh,
                                               OutT* __restrict__ Y,
                                               int Nloc, int K, int bm, int bn) {
    __shared__ __align__(16) unsigned short As[128 * 32];
    __shared__ __align__(16) unsigned short Bs[128 * 32];
    char* AsB = (char*)As;
    char* BsB = (char*)Bs;

    const int tid  = threadIdx.x;
    const int wave = tid >> 6, lane = tid & 63;
    const int wm = (wave >> 1) * 64, wn = (wave & 1) * 64;
    const int m = lane & 15, quad = lane >> 4;

    const int r0 = tid >> 2;
    const int cs = tid & 3;
    const int cg = cs ^ (r0 & 3);
    const int wbase = (tid & 192) * 16;

    const unsigned short* gA = Xh + (size_t)(bm + r0) * K + cg * 8;
    const unsigned short* gB = Wh + (size_t)(bn + r0) * K + cg * 8;
    const size_t rowStep64 = (size_t)64 * K;

    int aoff[4], boff[4];
#pragma unroll
    for (int mt = 0; mt < 4; ++mt) {
        int ra = wm + mt * 16 + m;
        aoff[mt] = ra * 64 + ((quad ^ (ra & 3)) * 16);
        int rb = wn + mt * 16 + m;
        boff[mt] = rb * 64 + ((quad ^ (rb & 3)) * 16);
    }

    f32x4 acc[4][4];
#pragma unroll
    for (int i = 0; i < 4; ++i)
#pragma unroll
        for (int j = 0; j < 4; ++j) acc[i][j] = (f32x4){0.f, 0.f, 0.f, 0.f};

    for (int k0 = 0; k0 < K; k0 += 32) {
        gl2lds16(gA,             AsB + wbase);
        gl2lds16(gA + rowStep64, AsB + 4096 + wbase);
        gl2lds16(gB,             BsB + wbase);
        gl2lds16(gB + rowStep64, BsB + 4096 + wbase);
        gA += 32;
        gB += 32;
        __syncthreads();

        bf16x8 af[4], bfr[4];
#pragma unroll
        for (int mt = 0; mt < 4; ++mt) af[mt]  = *(const bf16x8*)(AsB + aoff[mt]);
#pragma unroll
        for (int nt = 0; nt < 4; ++nt) bfr[nt] = *(const bf16x8*)(BsB + boff[nt]);
#pragma unroll
        for (int mt = 0; mt < 4; ++mt)
#pragma unroll
            for (int nt = 0; nt < 4; ++nt)
                acc[mt][nt] = __builtin_amdgcn_mfma_f32_16x16x32_bf16(af[mt], bfr[nt],
                                                                      acc[mt][nt], 0, 0, 0);
        __syncthreads();
    }

#pragma unroll
    for (int mt = 0; mt < 4; ++mt)
#pragma unroll
        for (int r = 0; r < 4; ++r) {
            size_t row = (size_t)(bm + wm + mt * 16 + quad * 4 + r);
#pragma unroll
            for (int nt = 0; nt < 4; ++nt) {
                int col = bn + wn + nt * 16 + m;
                float v = acc[mt][nt][r];
                if constexpr (sizeof(OutT) == 2)
                    Y[row * Nloc + col] = f2bf(v);
                else
                    Y[row * Nloc + col] = v;
            }
        }
}

__global__ __launch_bounds__(256) void qkv_gemm_bf16(const unsigned short* __restrict__ Xh,
                                                     const unsigned short* __restrict__ Wqh,
                                                     const unsigned short* __restrict__ Wkh,
                                                     const unsigned short* __restrict__ Wvh,
                                                     unsigned short* __restrict__ qh,
                                                     unsigned short* __restrict__ kh,
                                                     unsigned short* __restrict__ vh) {
    int bn0 = blockIdx.x * 128;
    const unsigned short* Wsel;
    unsigned short* Ysel;
    int bnl, Nloc;
    if (bn0 < H * D)                { Wsel = Wqh; Ysel = qh; bnl = bn0;                  Nloc = H * D;   }
    else if (bn0 < H*D + HKV*D)     { Wsel = Wkh; Ysel = kh; bnl = bn0 - H * D;          Nloc = HKV * D; }
    else                            { Wsel = Wvh; Ysel = vh; bnl = bn0 - H*D - HKV*D;    Nloc = HKV * D; }
    gemm_mfma_body<unsigned short>(Xh, Wsel, Ysel, Nloc, C, blockIdx.y * 128, bnl);
}

__global__ __launch_bounds__(256) void out_gemm_bf16(const unsigned short* __restrict__ Xh,
                                                     const unsigned short* __restrict__ Wh,
                                                     float* __restrict__ Y) {
    gemm_mfma_body<float>(Xh, Wh, Y, C, C, blockIdx.y * 128, blockIdx.x * 128);
}

// ---------------------------------------------------------------------------
// RoPE in-place on bf16; optional output prescale (folds softmax scale into Q)
// ---------------------------------------------------------------------------
__global__ void rope_bf16(unsigned short* __restrict__ buf, const int* __restrict__ pos_ids,
                          int nheads, int total, float outscale) {
    int idx = blockIdx.x * blockDim.x + threadIdx.x;
    if (idx >= total) return;
    int d = idx & 31;
    int rest = idx >> 5;                 // = (b*T + t)*nheads + h
    int t = (rest / nheads) % T;
    float pos = (float)pos_ids[t];
    int i1 = d >> 1;
    const float NEG_LF = -(2.0f / 64.0f) * 13.287712379549449f; // -2/D * log2(10000)
    float a1 = pos * exp2f(NEG_LF * (float)i1);
    float a2 = pos * exp2f(NEG_LF * (float)(i1 + 16));
    float c1 = cosf(a1), s1 = sinf(a1);
    float c2 = cosf(a2), s2 = sinf(a2);
    size_t base = (size_t)rest * D + d;
    float x1 = bf2f(buf[base]), x2 = bf2f(buf[base + 32]);
    buf[base]      = f2bf((x1 * c1 - x2 * s1) * outscale);
    buf[base + 32] = f2bf((x2 * c2 + x1 * s2) * outscale);
}

// ---------------------------------------------------------------------------
// V transpose bf16 [b][t][hkv][d] -> [b][hkv][d][t]
// ---------------------------------------------------------------------------
__global__ __launch_bounds__(256) void v_transpose(const unsigned short* __restrict__ vh,
                                                   unsigned short* __restrict__ vtg) {
    __shared__ unsigned short Vs[64][72];
    const int t0 = blockIdx.x * 64;
    const int hkv = blockIdx.y;
    const int b = blockIdx.z;
    const int tid = threadIdx.x;

    for (int e = tid; e < 512; e += 256) {
        int t = e >> 3, d8 = (e & 7) * 8;
        uint4 val = *(const uint4*)(vh + ((size_t)((b * T + t0 + t) * HKV) + hkv) * D + d8);
        unsigned short tmp[8];
        *(uint4*)tmp = val;
#pragma unroll
        for (int i = 0; i < 8; ++i) Vs[d8 + i][t] = tmp[i];
    }
    __syncthreads();
    for (int e = tid; e < 512; e += 256) {
        int d = e >> 3, c = e & 7;
        *(uint4*)(vtg + ((size_t)((b * HKV + hkv) * D) + d) * T + t0 + c * 8) =
            *(const uint4*)&Vs[d][c * 8];
    }
}

// ---------------------------------------------------------------------------
// bf16 MFMA flash attention v2 (fixed): S^T orientation, 128-query blocks,
// 32 queries/wave, base-2 softmax (Q pre-scaled by SCALE*log2e), gl2lds
// staging with 8-chunk XOR swizzle, wave-private P strip.
// FIX vs round 4: P pack uses scalar ushort stores (same-type LDS accesses —
// the uint2-typed pack could be reordered against the bf16x8 read by TBAA);
// alpha/l transposes use __shfl instead of hand-built ds_bpermute.
// ---------------------------------------------------------------------------
__global__ __launch_bounds__(256, 4) void flash_attn_mfma(const unsigned short* __restrict__ Qh,
                                                          const unsigned short* __restrict__ Kh,
                                                          const unsigned short* __restrict__ Vtg,
                                                          unsigned short* __restrict__ Yh) {
    __shared__ __align__(16) unsigned short Ks[64 * 64];   // [key][d], XOR-swizzled chunks
    __shared__ __align__(16) unsigned short Vt[64 * 64];   // [d][key], XOR-swizzled chunks
    __shared__ __align__(16) unsigned short Ps[4][32][72]; // per-wave P strip [query][key]

    const int q0 = ((int)gridDim.x - 1 - (int)blockIdx.x) * 128;   // heavy-first
    const int h  = blockIdx.y;
    const int b  = blockIdx.z;
    const int hkv = h >> 2;
    const int tid = threadIdx.x;
    const int wave = tid >> 6;
    const int lane = tid & 63;
    const int m = lane & 15;
    const int quad = lane >> 4;

    // Q B-frags: queries q0 + ct*64 + wave*16 + m
    bf16x8 qa[2][2];
#pragma unroll
    for (int ct = 0; ct < 2; ++ct) {
        const unsigned short* qrow =
            Qh + ((size_t)((b * T + q0 + ct * 64 + wave * 16 + m) * H) + h) * D;
        qa[ct][0] = *(const bf16x8*)(qrow + quad * 8);
        qa[ct][1] = *(const bf16x8*)(qrow + 32 + quad * 8);
    }

    f32x4 o[2][4];
#pragma unroll
    for (int ct = 0; ct < 2; ++ct)
#pragma unroll
        for (int dt = 0; dt < 4; ++dt) o[ct][dt] = (f32x4){0.f, 0.f, 0.f, 0.f};
    float ms[2] = {-1e30f, -1e30f};
    float ls[2] = {0.f, 0.f};

    // staging: thread t -> LDS slot t*16B (row r0=t>>3, chunk cs=t&7),
    // source chunk cg = cs ^ (r0&7)  (XOR applied on the global address)
    const int r0 = tid >> 3, cs = tid & 7, cg = cs ^ (r0 & 7);
    const int wbase = (tid & 192) * 16;
    const unsigned short* gK = Kh + ((size_t)(b * T) * HKV + hkv) * D
                                  + (size_t)r0 * (HKV * D) + cg * 8;
    const unsigned short* gV = Vtg + ((size_t)(b * HKV + hkv) * D) * (size_t)T
                                   + (size_t)r0 * T + cg * 8;
    char* KsB = (char*)Ks;
    char* VtB = (char*)Vt;

    const int kend = q0 + 127;
    for (int k0 = 0; k0 <= kend; k0 += 64) {
        gl2lds16(gK,                          KsB + wbase);
        gl2lds16(gK + (size_t)32 * (HKV * D), KsB + 4096 + wbase);
        gl2lds16(gV,                          VtB + wbase);
        gl2lds16(gV + (size_t)32 * T,         VtB + 4096 + wbase);
        gK += (size_t)64 * (HKV * D);
        gV += 64;
        __syncthreads();

#pragma unroll
        for (int ct = 0; ct < 2; ++ct) {
            const int qmin = q0 + ct * 64 + wave * 16;
            if (k0 > qmin + 15) continue;          // ct fully masked (wave-uniform)

            // ---- S^T = K · Q^T  (4 key-tiles of 16) ----
            f32x4 s[4];
#pragma unroll
            for (int nt = 0; nt < 4; ++nt) {
                const int kmin = k0 + nt * 16;
                if (kmin > qmin + 15) {            // fully masked tile
                    s[nt] = (f32x4){-1e30f, -1e30f, -1e30f, -1e30f};
                    continue;
                }
                int row = nt * 16 + m;
                const bf16x8 ka0 = *(const bf16x8*)(KsB + row * 128 + ((quad ^ (m & 7)) * 16));
                const bf16x8 ka1 = *(const bf16x8*)(KsB + row * 128 + (((quad + 4) ^ (m & 7)) * 16));
                f32x4 acc = (f32x4){0.f, 0.f, 0.f, 0.f};
                acc = __builtin_amdgcn_mfma_f32_16x16x32_bf16(ka0, qa[ct][0], acc, 0, 0, 0);
                acc = __builtin_amdgcn_mfma_f32_16x16x32_bf16(ka1, qa[ct][1], acc, 0, 0, 0);
                if (kmin + 15 > qmin) {            // diagonal: elementwise mask
                    int c0 = qmin - kmin + m - 4 * quad;   // mask if r > c0
#pragma unroll
                    for (int r = 0; r < 4; ++r)
                        if (r > c0) acc[r] = -1e30f;
                }
                s[nt] = acc;
            }

            // ---- base-2 online softmax (lane owns query m; reduce across quads) ----
            float mx = s[0][0];
#pragma unroll
            for (int nt = 0; nt < 4; ++nt)
#pragma unroll
                for (int r = 0; r < 4; ++r) mx = fmaxf(mx, s[nt][r]);
            mx = fmaxf(mx, __shfl_xor(mx, 16));
            mx = fmaxf(mx, __shfl_xor(mx, 32));
            float mnew = fmaxf(ms[ct], mx);
            float al = exp2f(ms[ct] - mnew);
            ms[ct] = mnew;
            float psum = 0.f;
#pragma unroll
            for (int nt = 0; nt < 4; ++nt)
#pragma unroll
                for (int r = 0; r < 4; ++r) {
                    float p = exp2f(s[nt][r] - mnew);
                    s[nt][r] = p;
                    psum += p;
                }
            psum += __shfl_xor(psum, 16);
            psum += __shfl_xor(psum, 32);
            ls[ct] = ls[ct] * al + psum;

            // ---- P -> wave-private LDS strip (scalar same-type stores) ----
#pragma unroll
            for (int nt = 0; nt < 4; ++nt)
#pragma unroll
                for (int r = 0; r < 4; ++r)
                    Ps[wave][ct * 16 + m][nt * 16 + quad * 4 + r] = f2bf(s[nt][r]);

            // ---- alpha transpose (query=m orient -> O-row orient) + rescale ----
            float av[4];
#pragma unroll
            for (int r = 0; r < 4; ++r)
                av[r] = __shfl(al, quad * 20 + r);   // lane with m' = quad*4+r
#pragma unroll
            for (int dt = 0; dt < 4; ++dt)
#pragma unroll
                for (int r = 0; r < 4; ++r) o[ct][dt][r] *= av[r];

            // ---- O += P · V ----
            const bf16x8 pa0 = *(const bf16x8*)&Ps[wave][ct * 16 + m][quad * 8];
            const bf16x8 pa1 = *(const bf16x8*)&Ps[wave][ct * 16 + m][32 + quad * 8];
#pragma unroll
            for (int dt = 0; dt < 4; ++dt) {
                int vrow = dt * 16 + m;
                const bf16x8 vb0 = *(const bf16x8*)(VtB + vrow * 128 + ((quad ^ (m & 7)) * 16));
                const bf16x8 vb1 = *(const bf16x8*)(VtB + vrow * 128 + (((quad + 4) ^ (m & 7)) * 16));
                o[ct][dt] = __builtin_amdgcn_mfma_f32_16x16x32_bf16(pa0, vb0, o[ct][dt], 0, 0, 0);
                o[ct][dt] = __builtin_amdgcn_mfma_f32_16x16x32_bf16(pa1, vb1, o[ct][dt], 0, 0, 0);
            }
        }
        __syncthreads();   // protect Ks/Vt before restage
    }

    // ---- epilogue: O / l -> bf16 y[b][t][h][d] ----
#pragma unroll
    for (int ct = 0; ct < 2; ++ct) {
#pragma unroll
        for (int r = 0; r < 4; ++r) {
            float lv = __shfl(ls[ct], quad * 20 + r);
            float inv = 1.0f / lv;
            int trow = q0 + ct * 64 + wave * 16 + quad * 4 + r;
            unsigned short* yp = Yh + ((size_t)(b * T + trow) * H + h) * D;
#pragma unroll
            for (int dt = 0; dt < 4; ++dt)
                yp[dt * 16 + m] = f2bf(o[ct][dt][r] * inv);
        }
    }
}

// ---------------------------------------------------------------------------
extern "C" void kernel_launch(void* const* d_in, const int* in_sizes, int n_in,
                              void* d_out, int out_size, void* d_ws, size_t ws_size,
                              hipStream_t stream) {
    const float* x  = (const float*)d_in[0];
    const float* Wq = (const float*)d_in[1];
    const float* Wk = (const float*)d_in[2];
    const float* Wv = (const float*)d_in[3];
    const float* Wc = (const float*)d_in[4];
    const int*  pos = (const int*)d_in[5];
    float* out = (float*)d_out;

    unsigned short* xh  = (unsigned short*)d_ws;           // B*T*C
    unsigned short* wqh = xh  + (size_t)B * T * C;
    unsigned short* wkh = wqh + (size_t)H * D * C;
    unsigned short* wvh = wkh + (size_t)HKV * D * C;
    unsigned short* wch = wvh + (size_t)HKV * D * C;
    unsigned short* qh  = wch + (size_t)C * C;
    unsigned short* kh  = qh  + (size_t)B * T * H * D;
    unsigned short* vh  = kh  + (size_t)B * T * HKV * D;
    unsigned short* vtg = vh  + (size_t)B * T * HKV * D;
    unsigned short* yh  = xh;                              // alias (xh dead after QKV)

    // 1) casts fp32 -> bf16
    cast_bf16<<<(B * T * C) / (256 * 8), 256, 0, stream>>>(x, xh, B * T * C);
    cast_bf16<<<(H * D * C) / (256 * 8), 256, 0, stream>>>(Wq, wqh, H * D * C);
    cast_bf16<<<(HKV * D * C) / (256 * 8), 256, 0, stream>>>(Wk, wkh, HKV * D * C);
    cast_bf16<<<(HKV * D * C) / (256 * 8), 256, 0, stream>>>(Wv, wvh, HKV * D * C);
    cast_bf16<<<(C * C) / (256 * 8), 256, 0, stream>>>(Wc, wch, C * C);

    // 2) fused QKV projection (bf16 MFMA)
    dim3 g1((H * D + 2 * HKV * D) / 128, (B * T) / 128);
    qkv_gemm_bf16<<<g1, 256, 0, stream>>>(xh, wqh, wkh, wvh, qh, kh, vh);

    // 3) RoPE (Q gets softmax scale folded in, base-2 domain); V transpose
    const float QSCALE = SCALE * 1.4426950408889634f;  // SCALE * log2(e)
    rope_bf16<<<(B * T * H * 32) / 256, 256, 0, stream>>>(qh, pos, H, B * T * H * 32, QSCALE);
    rope_bf16<<<(B * T * HKV * 32) / 256, 256, 0, stream>>>(kh, pos, HKV, B * T * HKV * 32, 1.0f);
    v_transpose<<<dim3(T / 64, HKV, B), 256, 0, stream>>>(vh, vtg);

    // 4) causal GQA flash attention (S^T orientation, 128-q blocks)
    dim3 g2(T / 128, H, B);
    flash_attn_mfma<<<g2, 256, 0, stream>>>(qh, kh, vtg, yh);

    // 5) output projection
    dim3 g3(C / 128, (B * T) / 128);
    out_gemm_bf16<<<g3, 256, 0, stream>>>(yh, wch, out);
}